// Round 1
// baseline (260.636 us; speedup 1.0000x reference)
//
#include <hip/hip_runtime.h>

#define FEAT 128

typedef __attribute__((ext_vector_type(8))) short short8;
typedef __attribute__((ext_vector_type(4))) float floatx4;

// bf16 helpers (manual, RNE) — finite data only.
__device__ __forceinline__ unsigned short f2bf(float f) {
    unsigned int u = __float_as_uint(f);
    u += 0x7fffu + ((u >> 16) & 1u);
    return (unsigned short)(u >> 16);
}
__device__ __forceinline__ float bf_lo(unsigned int u) { return __uint_as_float(u << 16); }
__device__ __forceinline__ float bf_hi(unsigned int u) { return __uint_as_float(u & 0xffff0000u); }
__device__ __forceinline__ unsigned int pack2(float a, float b) {
    return (unsigned int)f2bf(a) | ((unsigned int)f2bf(b) << 16);
}

// ===========================================================================
// Fused convert + histogram: stream x -> bf16 while the same threads issue
// the dst-histogram atomics (atomic latency hides under streaming traffic).
// ===========================================================================
__global__ __launch_bounds__(256) void convert_hist(const float* __restrict__ x,
                                                    unsigned short* __restrict__ xb,
                                                    long n4,
                                                    const int* __restrict__ dst,
                                                    int* __restrict__ counts, int E) {
    const long i = (long)blockIdx.x * 256 + threadIdx.x;
    if (i < E) atomicAdd(&counts[dst[i]], 1);
    if (i < n4) {
        const float4 v = *(const float4*)&x[i * 4];
        uint2 p;
        p.x = pack2(v.x, v.y);
        p.y = pack2(v.z, v.w);
        *(uint2*)&xb[i * 4] = p;
    }
}

// ===========================================================================
// Exclusive scan level 1: 256 threads x 4 elems = 1024-chunk per block.
// ===========================================================================
__global__ __launch_bounds__(256) void scan_chunk(const int* __restrict__ counts,
                                                  int* __restrict__ offsets,
                                                  int* __restrict__ blocksums, int N) {
    const int t = threadIdx.x;
    const int base = blockIdx.x * 1024 + t * 4;
    int c0 = (base + 0 < N) ? counts[base + 0] : 0;
    int c1 = (base + 1 < N) ? counts[base + 1] : 0;
    int c2 = (base + 2 < N) ? counts[base + 2] : 0;
    int c3 = (base + 3 < N) ? counts[base + 3] : 0;
    const int sum = c0 + c1 + c2 + c3;

    const int lane = t & 63, wv = t >> 6;
    int v = sum;
#pragma unroll
    for (int off = 1; off < 64; off <<= 1) {
        int n = __shfl_up(v, off);
        if (lane >= off) v += n;
    }
    __shared__ int ws[4];
    if (lane == 63) ws[wv] = v;
    __syncthreads();
    int wp = 0;
    for (int w = 0; w < wv; w++) wp += ws[w];
    int excl = wp + v - sum;

    if (base + 0 < N) offsets[base + 0] = excl;
    if (base + 1 < N) offsets[base + 1] = excl + c0;
    if (base + 2 < N) offsets[base + 2] = excl + c0 + c1;
    if (base + 3 < N) offsets[base + 3] = excl + c0 + c1 + c2;
    if (t == 255) blocksums[blockIdx.x] = wp + v;
}

// ===========================================================================
// Scan level 2 fused into add_base: each block (256 nodes, all in chunk
// c = blockIdx>>2) re-derives prefix(blocksums[0..c)) with wave 0 (<=2
// elems/lane for 98 chunks), then adds it. Also duplicates into cursor and
// caps offsets[N] = E.
// ===========================================================================
__global__ __launch_bounds__(256) void add_base(int* __restrict__ offsets,
                                                int* __restrict__ cursor,
                                                const int* __restrict__ blocksums,
                                                int N, int E) {
    __shared__ int sbase;
    const int c = blockIdx.x >> 2;       // this block's chunk id
    const int t = threadIdx.x;
    if (t < 64) {
        int s = 0;
        for (int j = t; j < c; j += 64) s += blocksums[j];
#pragma unroll
        for (int off = 32; off; off >>= 1) s += __shfl_down(s, off);
        if (t == 0) sbase = s;
    }
    __syncthreads();
    const int base = sbase;
    const int i = blockIdx.x * 256 + t;
    if (i < N) {
        const int off = offsets[i] + base;
        offsets[i] = off;
        cursor[i] = off;
    }
    if (i == 0) offsets[N] = E;
}

__global__ __launch_bounds__(256) void permute_kernel(const int* __restrict__ src,
                                                      const int* __restrict__ dst,
                                                      int* __restrict__ cursor,
                                                      int* __restrict__ sorted_src, int E) {
    const int e = blockIdx.x * 256 + threadIdx.x;
    if (e < E) {
        const int pos = atomicAdd(&cursor[dst[e]], 1);
        sorted_src[pos] = src[e];
    }
}

// ===========================================================================
// Both W matrices -> fragment-ordered bf16 for mfma_f32_16x16x32_bf16.
// bfW[((kc*8+ct)*64+lane)*8 + j] = bf16(W[kc*32 + (lane>>4)*8 + j][ct*16 + (lane&15)])
// blockIdx 0 -> W1, 1 -> W2.
// ===========================================================================
__global__ __launch_bounds__(256) void prep_w2(const float* __restrict__ W1,
                                               const float* __restrict__ W2,
                                               unsigned short* __restrict__ bfW1,
                                               unsigned short* __restrict__ bfW2) {
    const float* W = blockIdx.x ? W2 : W1;
    unsigned short* bfW = blockIdx.x ? bfW2 : bfW1;
    const int t = threadIdx.x;
#pragma unroll
    for (int it = 0; it < 8; it++) {
        const int idx = it * 256 + t;
        const int kc = idx >> 9;
        const int ct = (idx >> 6) & 7;
        const int lane = idx & 63;
        const int quad = lane >> 4;
        const int n = ct * 16 + (lane & 15);
        unsigned short frag[8];
#pragma unroll
        for (int j = 0; j < 8; j++) {
            const int k = kc * 32 + quad * 8 + j;
            frag[j] = f2bf(W[k * FEAT + n]);
        }
        *(uint4*)&bfW[(long)idx * 8] = *(uint4*)frag;
    }
}

// ===========================================================================
// FUSED gather + MFMA GEMM — zero LDS, no barriers, 128-THREAD blocks:
//   out_rows[i] = (sum_{e in CSR(i)} h[sorted_src[e]]) @ W + bias  [opt ReLU]
//
// Waves are fully independent; block size is only a scheduling quantum.
// 128 threads = 2 waves = 32 nodes/block -> 3125 blocks = 12.2 blocks/CU
// (fine-grained balance under the 16-WG/CU cap; round-6's 64-node blocks
// gave 6.1 blocks/CU and 42% occupancy).
// Lane (l15, quad) gathers node (blk*32 + wave*16 + l15), feature chunk
// kc*32+quad*8..+8 — the fp32 accumulator IS the MFMA A-fragment.
// B-frags straight from frag-ordered bfW in global (L1/L2-hot 32 KB).
// Epilogue stores from registers in C-layout (4 rows x 16-col segments).
// ===========================================================================
template <bool RELU, bool OUT_BF16>
__global__ __launch_bounds__(128, 8) void gather_gemm(const unsigned short* __restrict__ h,
                                                      const int* __restrict__ offsets,
                                                      const int* __restrict__ sorted_src,
                                                      const unsigned short* __restrict__ bfW,
                                                      const float* __restrict__ bias,
                                                      void* __restrict__ out, int N) {
    const int t = threadIdx.x;
    const int wave = t >> 6;
    const int lane = t & 63;
    const int quad = lane >> 4;
    const int l15 = lane & 15;
    const int node = blockIdx.x * 32 + wave * 16 + l15;

    int start = 0, end = 0;
    if (node < N) { start = offsets[node]; end = offsets[node + 1]; }

    const uint4* hb = (const uint4*)h;   // 16 uint4 per 128-feat row
    float acc[4][8];
#pragma unroll
    for (int kc = 0; kc < 4; kc++)
#pragma unroll
        for (int j = 0; j < 8; j++) acc[kc][j] = 0.f;

    // ---- gather phase (lane holds edges quad*2, quad*2+1 of node l15) ----
    int e0 = start + quad * 2;
    int s0 = (e0 < end) ? sorted_src[e0] : 0;
    int s1 = (e0 + 1 < end) ? sorted_src[e0 + 1] : 0;

    for (int eb = start; eb < end; eb += 8) {
        // Prefetch next batch's indices (hides index-load latency).
        const int ne = eb + 8 + quad * 2;
        const int ns0 = (ne < end) ? sorted_src[ne] : 0;
        const int ns1 = (ne + 1 < end) ? sorted_src[ne + 1] : 0;

        const int cnt = min(8, end - eb);
#pragma unroll 8
        for (int j = 0; j < cnt; j++) {
            const int sl = (j >> 1) * 16 + l15;        // lane holding edge eb+j of node l15
            const int s = __shfl((j & 1) ? s1 : s0, sl);
            const long rb = (long)s * 16;
            uint4 u[4];
#pragma unroll
            for (int kc = 0; kc < 4; kc++) u[kc] = hb[rb + kc * 4 + quad];
#pragma unroll
            for (int kc = 0; kc < 4; kc++) {
                acc[kc][0] += bf_lo(u[kc].x); acc[kc][1] += bf_hi(u[kc].x);
                acc[kc][2] += bf_lo(u[kc].y); acc[kc][3] += bf_hi(u[kc].y);
                acc[kc][4] += bf_lo(u[kc].z); acc[kc][5] += bf_hi(u[kc].z);
                acc[kc][6] += bf_lo(u[kc].w); acc[kc][7] += bf_hi(u[kc].w);
            }
        }
        s0 = ns0; s1 = ns1;
    }

    // acc -> A fragments (register-only; layout already matches).
    short8 afrag[4];
#pragma unroll
    for (int kc = 0; kc < 4; kc++) {
        unsigned short fr[8];
#pragma unroll
        for (int j = 0; j < 8; j++) fr[j] = f2bf(acc[kc][j]);
        afrag[kc] = *(short8*)fr;
    }

    // ---- MFMA phase: B-frags straight from global (L1/L2-hot 32 KB) ----
    floatx4 cacc[8];
#pragma unroll
    for (int ct = 0; ct < 8; ct++) cacc[ct] = (floatx4){0.f, 0.f, 0.f, 0.f};
#pragma unroll
    for (int kc = 0; kc < 4; kc++) {
#pragma unroll
        for (int ct = 0; ct < 8; ct++) {
            const short8 b = *(const short8*)&bfW[((kc * 8 + ct) * 64 + lane) * 8];
            cacc[ct] = __builtin_amdgcn_mfma_f32_16x16x32_bf16(afrag[kc], b, cacc[ct], 0, 0, 0);
        }
    }

    // ---- epilogue: C/D layout col=ct*16+l15, row=quad*4+r, direct stores.
#pragma unroll
    for (int ct = 0; ct < 8; ct++) {
        const int col = ct * 16 + l15;
        const float bv = bias[col];
#pragma unroll
        for (int r = 0; r < 4; r++) {
            const int row = blockIdx.x * 32 + wave * 16 + quad * 4 + r;
            if (row < N) {
                float v = cacc[ct][r] + bv;
                if (RELU) v = fmaxf(v, 0.f);
                if (OUT_BF16)
                    ((unsigned short*)out)[(long)row * FEAT + col] = f2bf(v);
                else
                    ((float*)out)[(long)row * FEAT + col] = v;
            }
        }
    }
}

// ===========================================================================
// Pipeline (bf16 payloads, fp32 accumulation):
//   counts=0; convert+hist; scan; add_base(+scan2); permute; prep_w
//   h1b = fused_gather_gemm(xb, W1, b1, relu) -> bf16
//   out = fused_gather_gemm(h1b, W2, b2)      -> fp32
// Linearity: segment_sum((hW)[src]) == (segment_sum h[src]) @ W.
// ===========================================================================
extern "C" void kernel_launch(void* const* d_in, const int* in_sizes, int n_in,
                              void* d_out, int out_size, void* d_ws, size_t ws_size,
                              hipStream_t stream) {
    const float* x  = (const float*)d_in[0];
    const int*   ei = (const int*)d_in[1];
    const float* W1 = (const float*)d_in[2];
    const float* b1 = (const float*)d_in[3];
    const float* W2 = (const float*)d_in[4];
    const float* b2 = (const float*)d_in[5];
    float* out = (float*)d_out;

    const int N = in_sizes[0] / FEAT;
    const int E = in_sizes[1] / 2;
    const int* src = ei;
    const int* dst = ei + E;

    // Workspace carve-up (~55 MB).
    unsigned short* xb   = (unsigned short*)d_ws;            // N*128 bf16
    unsigned short* h1b  = xb + (size_t)N * FEAT;            // N*128 bf16
    unsigned short* bfW1 = h1b + (size_t)N * FEAT;           // 16384
    unsigned short* bfW2 = bfW1 + 16384;                     // 16384
    int* counts    = (int*)(bfW2 + 16384);                   // [N]
    int* offsets   = counts + N;                             // [N+1]
    int* cursor    = offsets + N + 1;                        // [N]
    int* blocksums = cursor + N;                             // [<=128]
    int* sorted_src = blocksums + 128;                       // [E]

    const int NB = (N + 1023) / 1024;
    const int eb = (E + 255) / 256;
    const int nb = (N + 255) / 256;
    const long n4 = (long)N * FEAT / 4;

    // ---- CSR build + bf16 prep ----
    hipMemsetAsync(counts, 0, (size_t)N * sizeof(int), stream);
    convert_hist<<<(int)((n4 + 255) / 256), 256, 0, stream>>>(x, xb, n4, dst, counts, E);
    scan_chunk<<<NB, 256, 0, stream>>>(counts, offsets, blocksums, N);
    add_base<<<nb, 256, 0, stream>>>(offsets, cursor, blocksums, N, E);
    permute_kernel<<<eb, 256, 0, stream>>>(src, dst, cursor, sorted_src, E);
    prep_w2<<<2, 256, 0, stream>>>(W1, W2, bfW1, bfW2);

    const int fused_blocks = (N + 31) / 32;

    // ---- Layer 1 (bf16 out) / Layer 2 (fp32 out) ----
    gather_gemm<true, true><<<fused_blocks, 128, 0, stream>>>(
        xb, offsets, sorted_src, bfW1, b1, h1b, N);
    gather_gemm<false, false><<<fused_blocks, 128, 0, stream>>>(
        h1b, offsets, sorted_src, bfW2, b2, out, N);
}

// Round 2
// 259.183 us; speedup vs baseline: 1.0056x; 1.0056x over previous
//
#include <hip/hip_runtime.h>

#define FEAT 128

typedef __attribute__((ext_vector_type(8))) short short8;
typedef __attribute__((ext_vector_type(4))) float floatx4;

// bf16 helpers (manual, RNE) — finite data only.
__device__ __forceinline__ unsigned short f2bf(float f) {
    unsigned int u = __float_as_uint(f);
    u += 0x7fffu + ((u >> 16) & 1u);
    return (unsigned short)(u >> 16);
}
__device__ __forceinline__ float bf_lo(unsigned int u) { return __uint_as_float(u << 16); }
__device__ __forceinline__ float bf_hi(unsigned int u) { return __uint_as_float(u & 0xffff0000u); }
__device__ __forceinline__ unsigned int pack2(float a, float b) {
    return (unsigned int)f2bf(a) | ((unsigned int)f2bf(b) << 16);
}

// ===========================================================================
// Fused convert + histogram + W-prep:
//  blocks [0, chB): stream x -> bf16 while issuing dst-histogram atomics
//  blocks chB, chB+1: repack W1/W2 into MFMA fragment order (runs concurrent
//  with the streaming blocks instead of as a serial 2-block launch).
// ===========================================================================
__global__ __launch_bounds__(256) void convert_hist_prep(
        const float* __restrict__ x, unsigned short* __restrict__ xb, long n4,
        const int* __restrict__ dst, int* __restrict__ counts, int E,
        const float* __restrict__ W1, const float* __restrict__ W2,
        unsigned short* __restrict__ bfW1, unsigned short* __restrict__ bfW2,
        int chB) {
    const int t = threadIdx.x;
    if (blockIdx.x >= chB) {
        // ---- W repack: bfW[((kc*8+ct)*64+lane)*8+j] =
        //      bf16(W[kc*32 + (lane>>4)*8 + j][ct*16 + (lane&15)])
        const int wsel = blockIdx.x - chB;
        const float* W = wsel ? W2 : W1;
        unsigned short* bfW = wsel ? bfW2 : bfW1;
#pragma unroll
        for (int it = 0; it < 8; it++) {
            const int idx = it * 256 + t;
            const int kc = idx >> 9;
            const int ct = (idx >> 6) & 7;
            const int lane = idx & 63;
            const int quad = lane >> 4;
            const int n = ct * 16 + (lane & 15);
            unsigned short frag[8];
#pragma unroll
            for (int j = 0; j < 8; j++) {
                const int k = kc * 32 + quad * 8 + j;
                frag[j] = f2bf(W[k * FEAT + n]);
            }
            *(uint4*)&bfW[(long)idx * 8] = *(uint4*)frag;
        }
        return;
    }
    const long i = (long)blockIdx.x * 256 + t;
    if (i < E) atomicAdd(&counts[dst[i]], 1);
    if (i < n4) {
        const float4 v = *(const float4*)&x[i * 4];
        uint2 p;
        p.x = pack2(v.x, v.y);
        p.y = pack2(v.z, v.w);
        *(uint2*)&xb[i * 4] = p;
    }
}

// ===========================================================================
// Exclusive scan level 1: 256 threads x 4 elems = 1024-chunk per block.
// ===========================================================================
__global__ __launch_bounds__(256) void scan_chunk(const int* __restrict__ counts,
                                                  int* __restrict__ offsets,
                                                  int* __restrict__ blocksums, int N) {
    const int t = threadIdx.x;
    const int base = blockIdx.x * 1024 + t * 4;
    int c0 = (base + 0 < N) ? counts[base + 0] : 0;
    int c1 = (base + 1 < N) ? counts[base + 1] : 0;
    int c2 = (base + 2 < N) ? counts[base + 2] : 0;
    int c3 = (base + 3 < N) ? counts[base + 3] : 0;
    const int sum = c0 + c1 + c2 + c3;

    const int lane = t & 63, wv = t >> 6;
    int v = sum;
#pragma unroll
    for (int off = 1; off < 64; off <<= 1) {
        int n = __shfl_up(v, off);
        if (lane >= off) v += n;
    }
    __shared__ int ws[4];
    if (lane == 63) ws[wv] = v;
    __syncthreads();
    int wp = 0;
    for (int w = 0; w < wv; w++) wp += ws[w];
    int excl = wp + v - sum;

    if (base + 0 < N) offsets[base + 0] = excl;
    if (base + 1 < N) offsets[base + 1] = excl + c0;
    if (base + 2 < N) offsets[base + 2] = excl + c0 + c1;
    if (base + 3 < N) offsets[base + 3] = excl + c0 + c1 + c2;
    if (t == 255) blocksums[blockIdx.x] = wp + v;
}

// ===========================================================================
// Scan level 2 fused into add_base: each block (256 nodes, all in chunk
// c = blockIdx>>2) re-derives prefix(blocksums[0..c)) with wave 0, then adds
// it. Also duplicates into cursor and caps offsets[N] = E.
// ===========================================================================
__global__ __launch_bounds__(256) void add_base(int* __restrict__ offsets,
                                                int* __restrict__ cursor,
                                                const int* __restrict__ blocksums,
                                                int N, int E) {
    __shared__ int sbase;
    const int c = blockIdx.x >> 2;       // this block's chunk id
    const int t = threadIdx.x;
    if (t < 64) {
        int s = 0;
        for (int j = t; j < c; j += 64) s += blocksums[j];
#pragma unroll
        for (int off = 32; off; off >>= 1) s += __shfl_down(s, off);
        if (t == 0) sbase = s;
    }
    __syncthreads();
    const int base = sbase;
    const int i = blockIdx.x * 256 + t;
    if (i < N) {
        const int off = offsets[i] + base;
        offsets[i] = off;
        cursor[i] = off;
    }
    if (i == 0) offsets[N] = E;
}

__global__ __launch_bounds__(256) void permute_kernel(const int* __restrict__ src,
                                                      const int* __restrict__ dst,
                                                      int* __restrict__ cursor,
                                                      int* __restrict__ sorted_src, int E) {
    const int e = blockIdx.x * 256 + threadIdx.x;
    if (e < E) {
        const int pos = atomicAdd(&cursor[dst[e]], 1);
        sorted_src[pos] = src[e];
    }
}

// ===========================================================================
// FUSED gather + MFMA GEMM — zero LDS, no barriers, 128-THREAD blocks:
//   out_rows[i] = (sum_{e in CSR(i)} h[sorted_src[e]]) @ W + bias  [opt ReLU]
//
// Round-1 change: __launch_bounds__(128,4) (VGPR cap 64->128; measured
// occupancy was ~16 waves/CU anyway, so the 8-waves/EU squeeze to 32 VGPRs
// bought nothing and killed memory-level parallelism). Inner loop now
// processes edge PAIRS with unguarded loads: 8x16B loads in flight per lane
// before any accumulate (OOR partner loads row 0 — index already forced to
// 0 — and only the accumulate is masked), so load latency pipelines across
// the pair instead of draining per edge.
// ===========================================================================
__device__ __forceinline__ void acc_row(float acc[4][8], const uint4 u[4]) {
#pragma unroll
    for (int kc = 0; kc < 4; kc++) {
        acc[kc][0] += bf_lo(u[kc].x); acc[kc][1] += bf_hi(u[kc].x);
        acc[kc][2] += bf_lo(u[kc].y); acc[kc][3] += bf_hi(u[kc].y);
        acc[kc][4] += bf_lo(u[kc].z); acc[kc][5] += bf_hi(u[kc].z);
        acc[kc][6] += bf_lo(u[kc].w); acc[kc][7] += bf_hi(u[kc].w);
    }
}

template <bool RELU, bool OUT_BF16>
__global__ __launch_bounds__(128, 4) void gather_gemm(const unsigned short* __restrict__ h,
                                                      const int* __restrict__ offsets,
                                                      const int* __restrict__ sorted_src,
                                                      const unsigned short* __restrict__ bfW,
                                                      const float* __restrict__ bias,
                                                      void* __restrict__ out, int N) {
    const int t = threadIdx.x;
    const int wave = t >> 6;
    const int lane = t & 63;
    const int quad = lane >> 4;
    const int l15 = lane & 15;
    const int node = blockIdx.x * 32 + wave * 16 + l15;

    int start = 0, end = 0;
    if (node < N) { start = offsets[node]; end = offsets[node + 1]; }

    const uint4* hb = (const uint4*)h;   // 16 uint4 per 128-feat row
    float acc[4][8];
#pragma unroll
    for (int kc = 0; kc < 4; kc++)
#pragma unroll
        for (int j = 0; j < 8; j++) acc[kc][j] = 0.f;

    // ---- gather phase (lane holds edges quad*2, quad*2+1 of node l15) ----
    // All 4 quads of a given l15 share start/end, so every lane a shfl reads
    // from is at the same loop trip as the reader.
    int e0 = start + quad * 2;
    int s0 = (e0 < end) ? sorted_src[e0] : 0;
    int s1 = (e0 + 1 < end) ? sorted_src[e0 + 1] : 0;

    for (int eb = start; eb < end; eb += 8) {
        // Prefetch next batch's indices (hides index-load latency).
        const int ne = eb + 8 + quad * 2;
        const int ns0 = (ne < end) ? sorted_src[ne] : 0;
        const int ns1 = (ne + 1 < end) ? sorted_src[ne + 1] : 0;

        const int cnt = min(8, end - eb);
#pragma unroll
        for (int jp = 0; jp < 4; jp++) {
            const int j0 = jp * 2;
            if (j0 >= cnt) break;                     // divergent; same per l15 group
            const int sl = jp * 16 + l15;
            const int sA = __shfl(s0, sl);            // edge eb+2*jp
            const int sB = __shfl(s1, sl);            // edge eb+2*jp+1 (0 if OOR)
            const long rA = (long)sA * 16;
            const long rB = (long)sB * 16;
            uint4 uA[4], uB[4];
#pragma unroll
            for (int kc = 0; kc < 4; kc++) uA[kc] = hb[rA + kc * 4 + quad];
#pragma unroll
            for (int kc = 0; kc < 4; kc++) uB[kc] = hb[rB + kc * 4 + quad];
            acc_row(acc, uA);
            if (j0 + 1 < cnt) acc_row(acc, uB);       // mask only the accumulate
        }
        s0 = ns0; s1 = ns1;
    }

    // acc -> A fragments (register-only; layout already matches).
    short8 afrag[4];
#pragma unroll
    for (int kc = 0; kc < 4; kc++) {
        unsigned short fr[8];
#pragma unroll
        for (int j = 0; j < 8; j++) fr[j] = f2bf(acc[kc][j]);
        afrag[kc] = *(short8*)fr;
    }

    // ---- MFMA phase: B-frags straight from global (L1/L2-hot 32 KB) ----
    floatx4 cacc[8];
#pragma unroll
    for (int ct = 0; ct < 8; ct++) cacc[ct] = (floatx4){0.f, 0.f, 0.f, 0.f};
#pragma unroll
    for (int kc = 0; kc < 4; kc++) {
#pragma unroll
        for (int ct = 0; ct < 8; ct++) {
            const short8 b = *(const short8*)&bfW[((kc * 8 + ct) * 64 + lane) * 8];
            cacc[ct] = __builtin_amdgcn_mfma_f32_16x16x32_bf16(afrag[kc], b, cacc[ct], 0, 0, 0);
        }
    }

    // ---- epilogue: C/D layout col=ct*16+l15, row=quad*4+r, direct stores.
#pragma unroll
    for (int ct = 0; ct < 8; ct++) {
        const int col = ct * 16 + l15;
        const float bv = bias[col];
#pragma unroll
        for (int r = 0; r < 4; r++) {
            const int row = blockIdx.x * 32 + wave * 16 + quad * 4 + r;
            if (row < N) {
                float v = cacc[ct][r] + bv;
                if (RELU) v = fmaxf(v, 0.f);
                if (OUT_BF16)
                    ((unsigned short*)out)[(long)row * FEAT + col] = f2bf(v);
                else
                    ((float*)out)[(long)row * FEAT + col] = v;
            }
        }
    }
}

// ===========================================================================
// Pipeline (bf16 payloads, fp32 accumulation):
//   counts=0; convert+hist+prep_w; scan; add_base(+scan2); permute
//   h1b = fused_gather_gemm(xb, W1, b1, relu) -> bf16
//   out = fused_gather_gemm(h1b, W2, b2)      -> fp32
// Linearity: segment_sum((hW)[src]) == (segment_sum h[src]) @ W.
// ===========================================================================
extern "C" void kernel_launch(void* const* d_in, const int* in_sizes, int n_in,
                              void* d_out, int out_size, void* d_ws, size_t ws_size,
                              hipStream_t stream) {
    const float* x  = (const float*)d_in[0];
    const int*   ei = (const int*)d_in[1];
    const float* W1 = (const float*)d_in[2];
    const float* b1 = (const float*)d_in[3];
    const float* W2 = (const float*)d_in[4];
    const float* b2 = (const float*)d_in[5];
    float* out = (float*)d_out;

    const int N = in_sizes[0] / FEAT;
    const int E = in_sizes[1] / 2;
    const int* src = ei;
    const int* dst = ei + E;

    // Workspace carve-up (~55 MB).
    unsigned short* xb   = (unsigned short*)d_ws;            // N*128 bf16
    unsigned short* h1b  = xb + (size_t)N * FEAT;            // N*128 bf16
    unsigned short* bfW1 = h1b + (size_t)N * FEAT;           // 16384
    unsigned short* bfW2 = bfW1 + 16384;                     // 16384
    int* counts    = (int*)(bfW2 + 16384);                   // [N]
    int* offsets   = counts + N;                             // [N+1]
    int* cursor    = offsets + N + 1;                        // [N]
    int* blocksums = cursor + N;                             // [<=128]
    int* sorted_src = blocksums + 128;                       // [E]

    const int NB = (N + 1023) / 1024;
    const int eb = (E + 255) / 256;
    const int nb = (N + 255) / 256;
    const long n4 = (long)N * FEAT / 4;
    const int chB = (int)((n4 + 255) / 256);

    // ---- CSR build + bf16 prep (+ concurrent W repack) ----
    hipMemsetAsync(counts, 0, (size_t)N * sizeof(int), stream);
    convert_hist_prep<<<chB + 2, 256, 0, stream>>>(x, xb, n4, dst, counts, E,
                                                   W1, W2, bfW1, bfW2, chB);
    scan_chunk<<<NB, 256, 0, stream>>>(counts, offsets, blocksums, N);
    add_base<<<nb, 256, 0, stream>>>(offsets, cursor, blocksums, N, E);
    permute_kernel<<<eb, 256, 0, stream>>>(src, dst, cursor, sorted_src, E);

    const int fused_blocks = (N + 31) / 32;

    // ---- Layer 1 (bf16 out) / Layer 2 (fp32 out) ----
    gather_gemm<true, true><<<fused_blocks, 128, 0, stream>>>(
        xb, offsets, sorted_src, bfW1, b1, h1b, N);
    gather_gemm<false, false><<<fused_blocks, 128, 0, stream>>>(
        h1b, offsets, sorted_src, bfW2, b2, out, N);
}